// Round 2
// baseline (766.707 us; speedup 1.0000x reference)
//
#include <hip/hip_runtime.h>

// ---------------- types ----------------
typedef __attribute__((ext_vector_type(8))) short short8;
typedef __attribute__((ext_vector_type(4))) float f32x4;
typedef __attribute__((ext_vector_type(4))) unsigned short u16x4;

static __device__ __forceinline__ unsigned short f2bf(float x) {
  union { float f; unsigned u; } v; v.f = x;
  unsigned r = v.u + 0x7fffu + ((v.u >> 16) & 1u);   // round-to-nearest-even
  return (unsigned short)(r >> 16);
}
static __device__ __forceinline__ float bf2f(unsigned short h) {
  union { unsigned u; float f; } v; v.u = ((unsigned)h) << 16;
  return v.f;
}

// ---------------- fp32 -> bf16 (4 elems/thread) ----------------
__global__ __launch_bounds__(256) void to_bf16(const float* __restrict__ src,
                                               unsigned short* __restrict__ dst, int n4) {
  int i = blockIdx.x * blockDim.x + threadIdx.x;
  int stride = gridDim.x * blockDim.x;
  for (; i < n4; i += stride) {
    float4 x = *(const float4*)&src[i * 4];
    u16x4 o;
    o.x = f2bf(x.x); o.y = f2bf(x.y); o.z = f2bf(x.z); o.w = f2bf(x.w);
    *(u16x4*)&dst[i * 4] = o;
  }
}

// fp32 [rows][1024] -> bf16 [rows][3072].
// bmode 0: [hi | lo | hi] (A side)   bmode 1: [hi | hi | lo] (B side)
__global__ __launch_bounds__(256) void split3_bf16(const float* __restrict__ src,
                                                   unsigned short* __restrict__ dst,
                                                   int n, int bmode) {
  int i = blockIdx.x * blockDim.x + threadIdx.x;
  int stride = gridDim.x * blockDim.x;
  for (; i < n; i += stride) {
    int r = i >> 10, c = i & 1023;
    float x = src[i];
    unsigned short hi = f2bf(x);
    unsigned short lo = f2bf(x - bf2f(hi));
    unsigned short* row = dst + (size_t)r * 3072;
    if (bmode == 0) { row[c] = hi; row[1024 + c] = lo; row[2048 + c] = hi; }
    else            { row[c] = hi; row[1024 + c] = hi; row[2048 + c] = lo; }
  }
}

// ---------------- bf16 MFMA GEMM ----------------
// C[m][n] = sum_k A[m][k] * Bw[n][k] + bias[n]
// A: [4096][lda] bf16 (row-major, K-major), Bw: [1024][ldb] bf16 (N rows, K-major)
// mode 0: store permuted to [b][h][l][d] fp32 (b=m>>9, l=m&511, h=n>>6, d=n&63)
// mode 1: store plain [m][1024 + n]
__global__ __launch_bounds__(256) void gemm_bf16(const unsigned short* __restrict__ A, int lda,
                                                 const unsigned short* __restrict__ Bw, int ldb,
                                                 const float* __restrict__ bias,
                                                 float* __restrict__ Cout, int K, int mode) {
  __shared__ unsigned short As[128 * 32];
  __shared__ unsigned short Bs[128 * 32];
  const int t = threadIdx.x;
  const int lane = t & 63;
  const int w = t >> 6;
  const int wr = w >> 1, wc = w & 1;
  const int mt = blockIdx.x >> 3, nt = blockIdx.x & 7;
  const int m0 = mt * 128, n0 = nt * 128;
  const int r16 = lane & 15, kb = lane >> 4;   // kb in 0..3

  f32x4 acc[4][4];
#pragma unroll
  for (int mi = 0; mi < 4; ++mi)
#pragma unroll
    for (int ni = 0; ni < 4; ++ni) acc[mi][ni] = (f32x4){0.f, 0.f, 0.f, 0.f};

  for (int k0 = 0; k0 < K; k0 += 32) {
#pragma unroll
    for (int i = 0; i < 2; ++i) {
      int c = i * 256 + t;                 // 512 chunks of 8 bf16 (16 B)
      int row = c >> 2, kc = (c & 3) * 8;
      *(uint4*)&As[row * 32 + kc] = *(const uint4*)&A[(size_t)(m0 + row) * lda + k0 + kc];
      *(uint4*)&Bs[row * 32 + kc] = *(const uint4*)&Bw[(size_t)(n0 + row) * ldb + k0 + kc];
    }
    __syncthreads();
    short8 af[4], bf[4];
#pragma unroll
    for (int mi = 0; mi < 4; ++mi)
      af[mi] = *(const short8*)&As[(wr * 64 + mi * 16 + r16) * 32 + kb * 8];
#pragma unroll
    for (int ni = 0; ni < 4; ++ni)
      bf[ni] = *(const short8*)&Bs[(wc * 64 + ni * 16 + r16) * 32 + kb * 8];
#pragma unroll
    for (int mi = 0; mi < 4; ++mi)
#pragma unroll
      for (int ni = 0; ni < 4; ++ni)
        acc[mi][ni] = __builtin_amdgcn_mfma_f32_16x16x32_bf16(af[mi], bf[ni], acc[mi][ni], 0, 0, 0);
    __syncthreads();
  }

  const int rowD = (lane >> 4) * 4;
#pragma unroll
  for (int mi = 0; mi < 4; ++mi) {
#pragma unroll
    for (int ni = 0; ni < 4; ++ni) {
      int n = n0 + wc * 64 + ni * 16 + (lane & 15);
      float bv = bias[n];
#pragma unroll
      for (int j = 0; j < 4; ++j) {
        int m = m0 + wr * 64 + mi * 16 + rowD + j;
        float val = acc[mi][ni][j] + bv;
        if (mode == 0) {
          int b = m >> 9, l = m & 511, h = n >> 6, d = n & 63;
          Cout[(((size_t)(b * 16 + h)) * 512 + l) * 64 + d] = val;
        } else {
          Cout[(size_t)m * 1024 + n] = val;
        }
      }
    }
  }
}

// ---------------- fused attention (fp32) ----------------
// grid: 16 h * 64 l-tiles = 1024 wgs, 256 threads
// per wg: 8 query rows (l0..l0+7), all 8 batches; online softmax over r in tiles of 32.
// Epilogue writes hi/lo/hi bf16 split directly into Abig [4096][3072].
__global__ __launch_bounds__(256) void attn_kernel(const float* __restrict__ qh,
                                                   const float* __restrict__ kh,
                                                   const float* __restrict__ vh,
                                                   const float* __restrict__ rel,
                                                   const int* __restrict__ mask,
                                                   unsigned short* __restrict__ Abig) {
  __shared__ float qs[8][8][64];   // [b][l][d]
  __shared__ float sp[8][8][32];   // [b][l][rr] scores then p
  __shared__ float mst[8][8], sst[8][8], osc[8][8];
  const int t = threadIdx.x;
  const int h = blockIdx.x >> 6;
  const int l0 = (blockIdx.x & 63) * 8;

  // load q rows for all batches
#pragma unroll
  for (int i = 0; i < 4; ++i) {
    int f = i * 256 + t;                       // 1024 float4 chunks
    int b = f >> 7, l = (f >> 4) & 7, d4 = (f & 15) * 4;
    *(float4*)&qs[b][l][d4] =
        *(const float4*)&qh[(((size_t)(b * 16 + h)) * 512 + (l0 + l)) * 64 + d4];
  }
  if (t < 64) { int b = t >> 3, l = t & 7; mst[b][l] = -1e30f; sst[b][l] = 0.f; }

  float oacc[8][2];
#pragma unroll
  for (int l = 0; l < 8; ++l) { oacc[l][0] = 0.f; oacc[l][1] = 0.f; }

  const int bA = t >> 5;       // batch for passes A/D
  const int rr = t & 31;       // r within tile for passes A/B
  const int lB = t >> 5;       // l for pass B
  const int dp = t & 31;       // d-pair for pass D

  for (int r0 = 0; r0 < 512; r0 += 32) {
    __syncthreads();
    // ---- pass A: QK^T * scale ----
    {
      int r = r0 + rr;
      const float* kp = &kh[(((size_t)(bA * 16 + h)) * 512 + r) * 64];
      float accs[8] = {0, 0, 0, 0, 0, 0, 0, 0};
      for (int d0 = 0; d0 < 64; d0 += 4) {
        float4 kv = *(const float4*)&kp[d0];
#pragma unroll
        for (int l = 0; l < 8; ++l) {
          float4 qv = *(const float4*)&qs[bA][l][d0];
          accs[l] += qv.x * kv.x + qv.y * kv.y + qv.z * kv.z + qv.w * kv.w;
        }
      }
#pragma unroll
      for (int l = 0; l < 8; ++l) sp[bA][l][rr] = accs[l] * 0.125f;
    }
    __syncthreads();
    // ---- pass B: + q . rel (streams the 1 GiB rel tensor exactly once) ----
    {
      int r = r0 + rr;
      const float* rp = &rel[((size_t)(l0 + lB) * 512 + r) * 1024 + h * 64];
      float accg[8] = {0, 0, 0, 0, 0, 0, 0, 0};
      for (int d0 = 0; d0 < 64; d0 += 4) {
        float4 rv = *(const float4*)&rp[d0];
#pragma unroll
        for (int b = 0; b < 8; ++b) {
          float4 qv = *(const float4*)&qs[b][lB][d0];
          accg[b] += qv.x * rv.x + qv.y * rv.y + qv.z * rv.z + qv.w * rv.w;
        }
      }
#pragma unroll
      for (int b = 0; b < 8; ++b) sp[b][lB][rr] += accg[b];
    }
    __syncthreads();
    // ---- pass C: mask + online softmax update (64 threads) ----
    if (t < 64) {
      int b = t >> 3, l = t & 7;
      const int* mp = &mask[(size_t)(l0 + l) * 512 + r0];
      float mt = -1e30f;
      for (int i = 0; i < 32; ++i) {
        float vsc = sp[b][l][i];
        if (mp[i] == 0) vsc = -1e9f;
        sp[b][l][i] = vsc;
        mt = fmaxf(mt, vsc);
      }
      float mo = mst[b][l];
      float mn = fmaxf(mo, mt);
      float f = __expf(mo - mn);
      float s = sst[b][l] * f;
      for (int i = 0; i < 32; ++i) {
        float p = __expf(sp[b][l][i] - mn);
        sp[b][l][i] = p;
        s += p;
      }
      mst[b][l] = mn; sst[b][l] = s; osc[b][l] = f;
    }
    __syncthreads();
    // ---- pass D: rescale + PV ----
    {
#pragma unroll
      for (int l = 0; l < 8; ++l) {
        float f = osc[bA][l];
        oacc[l][0] *= f; oacc[l][1] *= f;
      }
      const float* vp = &vh[(((size_t)(bA * 16 + h)) * 512 + r0) * 64 + dp * 2];
      for (int i = 0; i < 32; ++i) {
        float2 vv = *(const float2*)&vp[(size_t)i * 64];
#pragma unroll
        for (int l = 0; l < 8; ++l) {
          float p = sp[bA][l][i];
          oacc[l][0] += p * vv.x;
          oacc[l][1] += p * vv.y;
        }
      }
    }
  }
  // ---- finalize: divide by sum; write hi/lo/hi bf16 split into Abig [m][3072] ----
#pragma unroll
  for (int l = 0; l < 8; ++l) {
    float inv = 1.0f / sst[bA][l];
    float ox = oacc[l][0] * inv;
    float oy = oacc[l][1] * inv;
    unsigned short hx = f2bf(ox), hy = f2bf(oy);
    unsigned short lx = f2bf(ox - bf2f(hx)), ly = f2bf(oy - bf2f(hy));
    unsigned short* rowp = Abig + (size_t)(bA * 512 + l0 + l) * 3072;
    int c = h * 64 + dp * 2;
    *(ushort2*)&rowp[c]        = make_ushort2(hx, hy);
    *(ushort2*)&rowp[1024 + c] = make_ushort2(lx, ly);
    *(ushort2*)&rowp[2048 + c] = make_ushort2(hx, hy);
  }
}

// ---------------- launcher ----------------
extern "C" void kernel_launch(void* const* d_in, const int* in_sizes, int n_in,
                              void* d_out, int out_size, void* d_ws, size_t ws_size,
                              hipStream_t stream) {
  const float* q    = (const float*)d_in[0];
  const float* k    = (const float*)d_in[1];
  const float* v    = (const float*)d_in[2];
  const float* rel  = (const float*)d_in[3];
  const int*   mask = (const int*)d_in[4];
  const float* Wq   = (const float*)d_in[5];
  const float* bq   = (const float*)d_in[6];
  const float* Wk   = (const float*)d_in[7];
  const float* bk   = (const float*)d_in[8];
  const float* Wv   = (const float*)d_in[9];
  const float* bv   = (const float*)d_in[10];
  const float* Wo   = (const float*)d_in[11];
  const float* bo   = (const float*)d_in[12];
  float* out = (float*)d_out;

  char* ws = (char*)d_ws;
  const size_t SZ_BHLD = (size_t)8 * 16 * 512 * 64 * 4;   // 16.78 MB each
  float* qh = (float*)(ws);
  float* kh = (float*)(ws + SZ_BHLD);
  float* vh = (float*)(ws + 2 * SZ_BHLD);
  // X region (25.17 MB): qbf/kbf/vbf during projections, then Abig [4096][3072]
  unsigned short* X = (unsigned short*)(ws + 3 * SZ_BHLD);
  // Y region (6.29 MB): Wq/Wk/Wv bf16 during projections, then Wo split [1024][3072]
  unsigned short* Y = (unsigned short*)(ws + 3 * SZ_BHLD + 25165824);
  unsigned short* qbf = X;
  unsigned short* kbf = X + 4194304;
  unsigned short* vbf = X + 8388608;
  unsigned short* Wqb = Y;
  unsigned short* Wkb = Y + 1048576;
  unsigned short* Wvb = Y + 2097152;

  // 1) convert inputs + weights to bf16 (4 elems/thread)
  to_bf16<<<1024, 256, 0, stream>>>(q, qbf, 1048576);
  to_bf16<<<1024, 256, 0, stream>>>(k, kbf, 1048576);
  to_bf16<<<1024, 256, 0, stream>>>(v, vbf, 1048576);
  to_bf16<<<256, 256, 0, stream>>>(Wq, Wqb, 262144);
  to_bf16<<<256, 256, 0, stream>>>(Wk, Wkb, 262144);
  to_bf16<<<256, 256, 0, stream>>>(Wv, Wvb, 262144);

  // 2) QKV projections -> [b][h][l][d] fp32
  gemm_bf16<<<256, 256, 0, stream>>>(qbf, 1024, Wqb, 1024, bq, qh, 1024, 0);
  gemm_bf16<<<256, 256, 0, stream>>>(kbf, 1024, Wkb, 1024, bk, kh, 1024, 0);
  gemm_bf16<<<256, 256, 0, stream>>>(vbf, 1024, Wvb, 1024, bv, vh, 1024, 0);

  // 3) Wo hi|hi|lo split into Y (overwrites dead Wq/Wk/Wv bf16)
  split3_bf16<<<1024, 256, 0, stream>>>(Wo, Y, 1048576, 1);

  // 4) fused attention (fp32, streams rel once); writes hi|lo|hi split into X
  attn_kernel<<<1024, 256, 0, stream>>>(qh, kh, vh, rel, mask, X);

  // 5) output projection, K=3072 split-GEMM -> d_out [4096][1024]
  gemm_bf16<<<256, 256, 0, stream>>>(X, 3072, Y, 3072, bo, out, 3072, 1);
}